// Round 1
// baseline (274.629 us; speedup 1.0000x reference)
//
#include <hip/hip_runtime.h>
#include <hip/hip_bf16.h>

// Problem constants (B=2, C=32, T=8, H=32, W=32, V=8192)
#define NQ    16384      // B*T*H*W
#define CDIM  32
#define VSZ   8192
#define PLANE 8192       // T*H*W
#define BSTR  262144     // C*PLANE
#define NEL   524288     // B*C*T*H*W

// ---------------- K1: codebook norms + zero counts/accumulators ----------------
__global__ void k_enorm(const float* __restrict__ emb, float* __restrict__ enorm,
                        int* __restrict__ counts, float* __restrict__ loss_sum) {
    int j = blockIdx.x * 256 + threadIdx.x;    // 8192 threads
    const float4* row = (const float4*)(emb + j * CDIM);
    float s = 0.f;
#pragma unroll
    for (int r = 0; r < 8; ++r) {
        float4 v = row[r];
        s += v.x * v.x + v.y * v.y + v.z * v.z + v.w * v.w;
    }
    enorm[j] = s;
    counts[j] = 0;
    if (j == 0) *loss_sum = 0.f;
}

// ---------------- K2: nearest-codebook argmin ----------------
// 512 blocks x 256 threads. Block owns 32 queries (QT=4 per thread, 8 q-groups),
// V split 32 ways (vs = tid>>3, entries j == vs mod 32 within each chunk).
#define QB 32
#define CH 256
#define ESTRIDE 40   // padded row stride in floats: 160B, 16B aligned, bank-friendly

__global__ __launch_bounds__(256, 2) void k_argmin(
    const float* __restrict__ f, const float* __restrict__ emb,
    const float* __restrict__ enorm, int* __restrict__ out_idx,
    int* __restrict__ counts) {
    __shared__ float e_s[CH * ESTRIDE];
    __shared__ float en_s[CH];
    __shared__ float red_v[QB * 32];
    __shared__ int   red_i[QB * 32];

    const int tid = threadIdx.x;
    const int qg = tid & 7;    // query group 0..7
    const int vs = tid >> 3;   // V segment 0..31
    const int qbase = blockIdx.x * QB;

    // Load this thread's 4 query vectors into registers (channel stride PLANE)
    float q[4][CDIM];
    {
        int n0 = qbase + qg * 4;
#pragma unroll
        for (int qi = 0; qi < 4; ++qi) {
            int n = n0 + qi;
            int b = n >> 13, p = n & (PLANE - 1);
            const float* fq = f + b * BSTR + p;
#pragma unroll
            for (int c = 0; c < CDIM; ++c) q[qi][c] = fq[c * PLANE];
        }
    }

    float best[4] = {1e30f, 1e30f, 1e30f, 1e30f};
    int   bidx[4] = {0, 0, 0, 0};

    for (int cb = 0; cb < VSZ; cb += CH) {
        __syncthreads();
        // Stage CH codebook rows (row-major, padded stride) + their norms
        {
            const float4* src = (const float4*)(emb + cb * CDIM);
#pragma unroll
            for (int r = 0; r < 8; ++r) {
                int g = tid + 256 * r;            // quad index 0..2047
                float4 v = src[g];
                int j = g >> 3, c0 = (g & 7) * 4;
                *(float4*)&e_s[j * ESTRIDE + c0] = v;
            }
            en_s[tid] = enorm[cb + tid];
        }
        __syncthreads();

#pragma unroll 2
        for (int i = 0; i < CH / 32; ++i) {
            int j = vs + 32 * i;
            const float* er = &e_s[j * ESTRIDE];
            float e[CDIM];
#pragma unroll
            for (int c0 = 0; c0 < CDIM; c0 += 4) {
                float4 v = *(const float4*)&er[c0];
                e[c0] = v.x; e[c0 + 1] = v.y; e[c0 + 2] = v.z; e[c0 + 3] = v.w;
            }
            float acc[4] = {0.f, 0.f, 0.f, 0.f};
#pragma unroll
            for (int c = 0; c < CDIM; ++c) {
#pragma unroll
                for (int qi = 0; qi < 4; ++qi)
                    acc[qi] = fmaf(q[qi][c], e[c], acc[qi]);
            }
            float en = en_s[j];
#pragma unroll
            for (int qi = 0; qi < 4; ++qi) {
                float d = en - 2.0f * acc[qi];
                if (d < best[qi]) { best[qi] = d; bidx[qi] = cb + j; }
            }
        }
    }

    __syncthreads();
#pragma unroll
    for (int qi = 0; qi < 4; ++qi) {
        int ql = qg * 4 + qi;
        red_v[ql * 32 + vs] = best[qi];
        red_i[ql * 32 + vs] = bidx[qi];
    }
    __syncthreads();
    if (tid < QB) {
        int ql = tid;
        float bv = red_v[ql * 32];
        int   bi = red_i[ql * 32];
        for (int v2 = 1; v2 < 32; ++v2) {
            float vv = red_v[ql * 32 + v2];
            int   ii = red_i[ql * 32 + v2];
            if (vv < bv || (vv == bv && ii < bi)) { bv = vv; bi = ii; }
        }
        int n = qbase + ql;
        out_idx[n] = bi;
        atomicAdd(&counts[bi], 1);
    }
}

// ---------------- K3: gather emb[idx] into [B,C,T,H,W] layout ----------------
__global__ void k_gather(const int* __restrict__ idx, const float* __restrict__ emb,
                         float* __restrict__ fh) {
    int n = blockIdx.x * 256 + threadIdx.x;   // 16384
    int id = idx[n];
    int b = n >> 13, p = n & (PLANE - 1);
    const float4* row = (const float4*)(emb + id * CDIM);
    float* dst = fh + b * BSTR + p;
#pragma unroll
    for (int r = 0; r < 8; ++r) {
        float4 v = row[r];
        dst[(r * 4 + 0) * PLANE] = v.x;
        dst[(r * 4 + 1) * PLANE] = v.y;
        dst[(r * 4 + 2) * PLANE] = v.z;
        dst[(r * 4 + 3) * PLANE] = v.w;
    }
}

// ---------------- K4: 3x3x3 conv (k-split over dt,dh; fp32 atomics) ----------------
__global__ __launch_bounds__(256) void k_conv(const float* __restrict__ fh,
                                              const float* __restrict__ w,
                                              float* __restrict__ conv) {
    int seg = blockIdx.x >> 6;     // 0..8
    int nb = blockIdx.x & 63;
    int n = nb * 256 + threadIdx.x;   // 0..16383
    int dt = seg / 3 - 1, dh = seg % 3 - 1;
    int b = n >> 13, p = n & (PLANE - 1);
    int t = p >> 10, h = (p >> 5) & 31, wi = p & 31;
    int tt = t + dt, hh = h + dh;
    bool tv = ((unsigned)tt < 8u);
    bool hv = ((unsigned)hh < 32u);
    int tc = min(max(tt, 0), 7), hc = min(max(hh, 0), 31);
    float acc[CDIM];
#pragma unroll
    for (int co = 0; co < CDIM; ++co) acc[co] = 0.f;

    const float* xbase = fh + b * BSTR + tc * 1024 + hc * 32;
    int wbase0 = (dt + 1) * 9 + (dh + 1) * 3;

    for (int ci = 0; ci < CDIM; ++ci) {
        const float* xr = xbase + ci * PLANE;
        int wb_ci = wbase0 + ci * 27;
#pragma unroll
        for (int kw = 0; kw < 3; ++kw) {
            int wwi = wi + kw - 1;
            bool ok = tv && hv && ((unsigned)wwi < 32u);
            int wc = min(max(wwi, 0), 31);
            float x = xr[wc];
            x = ok ? x : 0.f;
            int wb = wb_ci + kw;
#pragma unroll
            for (int co = 0; co < CDIM; ++co)
                acc[co] = fmaf(w[co * 864 + wb], x, acc[co]);
        }
    }
    float* dst = conv + b * BSTR + p;
#pragma unroll
    for (int co = 0; co < CDIM; ++co) atomicAdd(&dst[co * PLANE], acc[co]);
}

// ---------------- K5: blend + write fhat + loss partial reduction ----------------
__global__ void k_final(const float* __restrict__ fh, const float* __restrict__ conv,
                        const float* __restrict__ bias, const float* __restrict__ f,
                        float* __restrict__ out, float* __restrict__ loss_sum) {
    int gid = blockIdx.x * 256 + threadIdx.x;  // 131072 threads, 4 elems each
    int i = gid * 4;
    int c = (i >> 13) & 31;
    float4 a = *(const float4*)(fh + i);
    float4 cv = *(const float4*)(conv + i);
    float4 fv = *(const float4*)(f + i);
    float bb = bias[c];
    float4 o;
    o.x = 0.5f * a.x + 0.5f * (cv.x + bb);
    o.y = 0.5f * a.y + 0.5f * (cv.y + bb);
    o.z = 0.5f * a.z + 0.5f * (cv.z + bb);
    o.w = 0.5f * a.w + 0.5f * (cv.w + bb);
    *(float4*)(out + i) = o;
    float dx = o.x - fv.x, dy = o.y - fv.y, dz = o.z - fv.z, dw = o.w - fv.w;
    float s = dx * dx + dy * dy + dz * dz + dw * dw;
#pragma unroll
    for (int off = 32; off > 0; off >>= 1) s += __shfl_down(s, off, 64);
    __shared__ float ls[4];
    if ((threadIdx.x & 63) == 0) ls[threadIdx.x >> 6] = s;
    __syncthreads();
    if (threadIdx.x == 0) atomicAdd(loss_sum, ls[0] + ls[1] + ls[2] + ls[3]);
}

// ---------------- K6: scalars (vq_loss, vocab_usage) ----------------
__global__ void k_scalars(const int* __restrict__ counts,
                          const float* __restrict__ loss_sum, float* __restrict__ out) {
    int tid = threadIdx.x;
    int used = 0;
#pragma unroll
    for (int r = 0; r < 32; ++r) used += (counts[tid + 256 * r] > 0) ? 1 : 0;
#pragma unroll
    for (int off = 32; off > 0; off >>= 1) used += __shfl_down(used, off, 64);
    __shared__ int us[4];
    if ((tid & 63) == 0) us[tid >> 6] = used;
    __syncthreads();
    if (tid == 0) {
        int u = us[0] + us[1] + us[2] + us[3];
        out[NEL + 0] = 1.25f * (*loss_sum) / (float)NEL;          // vq_loss
        out[NEL + 1] = ((float)u / (float)VSZ) * 100.0f;          // vocab_usage
    }
}

extern "C" void kernel_launch(void* const* d_in, const int* in_sizes, int n_in,
                              void* d_out, int out_size, void* d_ws, size_t ws_size,
                              hipStream_t stream) {
    const float* f      = (const float*)d_in[0];
    const float* emb    = (const float*)d_in[1];
    const float* conv_w = (const float*)d_in[2];
    const float* conv_b = (const float*)d_in[3];
    float* out = (float*)d_out;
    float* ws = (float*)d_ws;

    float* enorm    = ws;                        // 8192 floats
    int*   idxb     = (int*)(ws + 8192);         // 16384 ints
    int*   counts   = (int*)(ws + 24576);        // 8192 ints
    float* loss_sum = ws + 32768;                // 1 float (+pad)
    float* fh       = ws + 33024;                // 524288 floats
    float* conv     = ws + 557312;               // 524288 floats

    hipMemsetAsync(conv, 0, NEL * sizeof(float), stream);
    k_enorm<<<32, 256, 0, stream>>>(emb, enorm, counts, loss_sum);
    k_argmin<<<512, 256, 0, stream>>>(f, emb, enorm, idxb, counts);
    k_gather<<<64, 256, 0, stream>>>(idxb, emb, fh);
    k_conv<<<576, 256, 0, stream>>>(fh, conv_w, conv);
    k_final<<<512, 256, 0, stream>>>(fh, conv, conv_b, f, out, loss_sum);
    k_scalars<<<1, 256, 0, stream>>>(counts, loss_sum, out);
}

// Round 2
// 257.401 us; speedup vs baseline: 1.0669x; 1.0669x over previous
//
#include <hip/hip_runtime.h>
#include <hip/hip_bf16.h>

// Problem constants (B=2, C=32, T=8, H=32, W=32, V=8192)
#define NQ    16384      // B*T*H*W
#define CDIM  32
#define VSZ   8192
#define PLANE 8192       // T*H*W
#define BSTR  262144     // C*PLANE
#define NEL   524288     // B*C*T*H*W

typedef unsigned long long u64;

// ---------------- K1: codebook norms + zero counts + zero loss ----------------
__global__ void k_enorm(const float* __restrict__ emb, float* __restrict__ enorm,
                        int* __restrict__ counts, float* __restrict__ loss_sum) {
    int j = blockIdx.x * 256 + threadIdx.x;    // 8192 threads
    const float4* row = (const float4*)(emb + j * CDIM);
    float s = 0.f;
#pragma unroll
    for (int r = 0; r < 8; ++r) {
        float4 v = row[r];
        s += v.x * v.x + v.y * v.y + v.z * v.z + v.w * v.w;
    }
    enorm[j] = s;
    counts[j] = 0;
    if (j == 0) *loss_sum = 0.f;
}

// ---------------- K2: nearest-codebook argmin ----------------
// 1024 blocks x 256 threads. Block owns 16 queries (QT=2 per thread, 8 q-groups),
// V split 32 ways across threads (vs = tid>>3).
#define QT 2
#define QB 16
#define CH 256
#define ESTRIDE 36   // 144 B row stride: 16B aligned, conflict-free for vs-strided b128 reads

__global__ __launch_bounds__(256, 4) void k_argmin(
    const float* __restrict__ f, const float* __restrict__ emb,
    const float* __restrict__ enorm, int* __restrict__ out_idx,
    int* __restrict__ counts) {
    __shared__ float e_s[CH * ESTRIDE];       // 36864 B
    __shared__ float en_s[CH];                // 1024 B
    __shared__ u64  wred[4 * QB];             // 512 B: [wave][ql]

    const int tid = threadIdx.x;
    const int qg = tid & 7;    // query group 0..7
    const int vs = tid >> 3;   // V segment 0..31
    const int qbase = blockIdx.x * QB;

    // Load this thread's 2 query vectors, pre-scaled by -2 (argmin of ||e||^2 - 2 q.e)
    float q[QT][CDIM];
    {
        int n0 = qbase + qg * QT;
#pragma unroll
        for (int qi = 0; qi < QT; ++qi) {
            int n = n0 + qi;
            int b = n >> 13, p = n & (PLANE - 1);
            const float* fq = f + b * BSTR + p;
#pragma unroll
            for (int c = 0; c < CDIM; ++c) q[qi][c] = -2.0f * fq[c * PLANE];
        }
    }

    float best[QT] = {1e30f, 1e30f};
    int   bidx[QT] = {0, 0};

    for (int cb = 0; cb < VSZ; cb += CH) {
        __syncthreads();
        // Stage CH codebook rows (row-major, padded stride) + norms
        {
            const float4* src = (const float4*)(emb + cb * CDIM);
#pragma unroll
            for (int r = 0; r < 8; ++r) {
                int g = tid + 256 * r;            // quad index 0..2047
                float4 v = src[g];
                *(float4*)&e_s[(g >> 3) * ESTRIDE + (g & 7) * 4] = v;
            }
            en_s[tid] = enorm[cb + tid];
        }
        __syncthreads();

#pragma unroll 2
        for (int i = 0; i < CH / 32; ++i) {
            int j = vs + 32 * i;
            const float* er = &e_s[j * ESTRIDE];
            float e[CDIM];
#pragma unroll
            for (int c0 = 0; c0 < CDIM; c0 += 4) {
                float4 v = *(const float4*)&er[c0];
                e[c0] = v.x; e[c0 + 1] = v.y; e[c0 + 2] = v.z; e[c0 + 3] = v.w;
            }
            float en = en_s[j];
            float acc[QT];
#pragma unroll
            for (int qi = 0; qi < QT; ++qi) acc[qi] = en;
#pragma unroll
            for (int c = 0; c < CDIM; ++c) {
#pragma unroll
                for (int qi = 0; qi < QT; ++qi)
                    acc[qi] = fmaf(q[qi][c], e[c], acc[qi]);
            }
            int jj = cb + j;
#pragma unroll
            for (int qi = 0; qi < QT; ++qi) {
                if (acc[qi] < best[qi]) { best[qi] = acc[qi]; bidx[qi] = jj; }
            }
        }
    }

    // Pack (dist, idx) into order-preserving u64; min == (min dist, tie -> min idx)
    u64 key[QT];
#pragma unroll
    for (int qi = 0; qi < QT; ++qi) {
        unsigned int b32 = __float_as_uint(best[qi]);
        b32 = (b32 & 0x80000000u) ? ~b32 : (b32 | 0x80000000u);
        key[qi] = ((u64)b32 << 32) | (unsigned int)bidx[qi];
    }
    // Butterfly over vs-within-wave (tid bits 3..5)
#pragma unroll
    for (int off = 8; off <= 32; off <<= 1) {
#pragma unroll
        for (int qi = 0; qi < QT; ++qi) {
            u64 other = __shfl_xor(key[qi], off, 64);
            if (other < key[qi]) key[qi] = other;
        }
    }
    if ((tid & 56) == 0) {   // one lane per qg per wave
#pragma unroll
        for (int qi = 0; qi < QT; ++qi)
            wred[(tid >> 6) * QB + qg * QT + qi] = key[qi];
    }
    __syncthreads();
    if (tid < QB) {
        u64 k = wred[tid];
#pragma unroll
        for (int w = 1; w < 4; ++w) {
            u64 o = wred[w * QB + tid];
            if (o < k) k = o;
        }
        int id = (int)(k & 0xFFFFFFFFull);
        out_idx[qbase + tid] = id;
        atomicAdd(&counts[id], 1);
    }
}

// ---------------- K3: gather emb[idx] into [B,C,T,H,W] layout ----------------
__global__ void k_gather(const int* __restrict__ idx, const float* __restrict__ emb,
                         float* __restrict__ fh) {
    int n = blockIdx.x * 256 + threadIdx.x;   // 16384
    int id = idx[n];
    int b = n >> 13, p = n & (PLANE - 1);
    const float4* row = (const float4*)(emb + id * CDIM);
    float* dst = fh + b * BSTR + p;
#pragma unroll
    for (int r = 0; r < 8; ++r) {
        float4 v = row[r];
        dst[(r * 4 + 0) * PLANE] = v.x;
        dst[(r * 4 + 1) * PLANE] = v.y;
        dst[(r * 4 + 2) * PLANE] = v.z;
        dst[(r * 4 + 3) * PLANE] = v.w;
    }
}

// ---------------- K4: fused conv3x3x3 + blend + fhat store + loss ----------------
// grid 512 = 64 spatial blocks x 8 co-groups (4 co each). Thread = 1 spatial point.
// Weights are block-uniform -> scalar loads. x via 3 plane pointers + imm offsets.
__global__ __launch_bounds__(256) void k_conv(const float* __restrict__ fh,
                                              const float* __restrict__ cw,
                                              const float* __restrict__ bias,
                                              const float* __restrict__ f,
                                              float* __restrict__ out,
                                              float* __restrict__ loss_sum) {
    const int tid = threadIdx.x;
    const int n = (blockIdx.x & 63) * 256 + tid;   // 0..16383
    const int cog = blockIdx.x >> 6;               // 0..7
    const int b = n >> 13, p = n & (PLANE - 1);
    const int t = p >> 10, h = (p >> 5) & 31, wi = p & 31;

    // boundary masks for the 27 taps
    float msk[27];
#pragma unroll
    for (int dt = 0; dt < 3; ++dt)
#pragma unroll
        for (int dh = 0; dh < 3; ++dh)
#pragma unroll
            for (int dw = 0; dw < 3; ++dw) {
                bool ok = ((unsigned)(t + dt - 1) < 8u) &&
                          ((unsigned)(h + dh - 1) < 32u) &&
                          ((unsigned)(wi + dw - 1) < 32u);
                msk[dt * 9 + dh * 3 + dw] = ok ? 1.0f : 0.0f;
            }

    const float* xb = fh + b * BSTR + p;           // + ci*PLANE per channel
    const float* wp = cw + cog * 4 * 864;          // weights for this co-group
    float acc[4] = {0.f, 0.f, 0.f, 0.f};

    for (int ci = 0; ci < CDIM; ++ci) {
        const float* xr = xb + ci * PLANE;
        const float* x0 = xr - 1024;
        const float* x1 = xr;
        const float* x2 = xr + 1024;
#pragma unroll
        for (int dt = 0; dt < 3; ++dt) {
            const float* xp = (dt == 0) ? x0 : ((dt == 1) ? x1 : x2);
#pragma unroll
            for (int dh = 0; dh < 3; ++dh) {
#pragma unroll
                for (int dw = 0; dw < 3; ++dw) {
                    int u = dt * 9 + dh * 3 + dw;
                    float x = xp[(dh - 1) * 32 + (dw - 1)] * msk[u];
#pragma unroll
                    for (int k = 0; k < 4; ++k)
                        acc[k] = fmaf(wp[k * 864 + ci * 27 + u], x, acc[k]);
                }
            }
        }
    }

    // blend: fhat = 0.5*fh + 0.5*(conv + bias); loss partial = sum (fhat - f)^2
    float s = 0.f;
#pragma unroll
    for (int k = 0; k < 4; ++k) {
        int co = cog * 4 + k;
        long off = (long)b * BSTR + (long)co * PLANE + p;
        float fhc = fh[off];
        float fv = f[off];
        float o = 0.5f * fhc + 0.5f * (acc[k] + bias[co]);
        out[off] = o;
        float d = o - fv;
        s = fmaf(d, d, s);
    }
#pragma unroll
    for (int off = 32; off > 0; off >>= 1) s += __shfl_down(s, off, 64);
    __shared__ float ls[4];
    if ((tid & 63) == 0) ls[tid >> 6] = s;
    __syncthreads();
    if (tid == 0) atomicAdd(loss_sum, ls[0] + ls[1] + ls[2] + ls[3]);
}

// ---------------- K5: scalars (vq_loss, vocab_usage) ----------------
__global__ void k_scalars(const int* __restrict__ counts,
                          const float* __restrict__ loss_sum, float* __restrict__ out) {
    int tid = threadIdx.x;
    int used = 0;
#pragma unroll
    for (int r = 0; r < 32; ++r) used += (counts[tid + 256 * r] > 0) ? 1 : 0;
#pragma unroll
    for (int off = 32; off > 0; off >>= 1) used += __shfl_down(used, off, 64);
    __shared__ int us[4];
    if ((tid & 63) == 0) us[tid >> 6] = used;
    __syncthreads();
    if (tid == 0) {
        int u = us[0] + us[1] + us[2] + us[3];
        out[NEL + 0] = 1.25f * (*loss_sum) / (float)NEL;          // vq_loss
        out[NEL + 1] = ((float)u / (float)VSZ) * 100.0f;          // vocab_usage
    }
}

extern "C" void kernel_launch(void* const* d_in, const int* in_sizes, int n_in,
                              void* d_out, int out_size, void* d_ws, size_t ws_size,
                              hipStream_t stream) {
    const float* f      = (const float*)d_in[0];
    const float* emb    = (const float*)d_in[1];
    const float* conv_w = (const float*)d_in[2];
    const float* conv_b = (const float*)d_in[3];
    float* out = (float*)d_out;
    float* ws = (float*)d_ws;

    float* enorm    = ws;                         // 8192 floats
    int*   idxb     = (int*)(ws + 8192);          // 16384 ints
    int*   counts   = (int*)(ws + 24576);         // 8192 ints
    float* loss_sum = ws + 32768;                 // 1 float (+pad to 33024)
    // fh with 2048-float guard margins on both sides (masked OOB conv reads)
    float* fh       = ws + 33024 + 2048;          // 524288 floats

    k_enorm<<<32, 256, 0, stream>>>(emb, enorm, counts, loss_sum);
    k_argmin<<<1024, 256, 0, stream>>>(f, emb, enorm, idxb, counts);
    k_gather<<<64, 256, 0, stream>>>(idxb, emb, fh);
    k_conv<<<512, 256, 0, stream>>>(fh, conv_w, conv_b, f, out, loss_sum);
    k_scalars<<<1, 256, 0, stream>>>(counts, loss_sum, out);
}